// Round 8
// baseline (212.488 us; speedup 1.0000x reference)
//
#include <hip/hip_runtime.h>
#include <hip/hip_bf16.h>

// StyleLoss — x (1,512,64,64) fp32, target (512,256,256) fp32 -> scalar loss.
// loss = mean_{i,a,b}( (g_full[(i+a)%512,(i+b)%512]/2^20 - target[i,a,b])^2 ) * 1e6
//
// R11: same algebra as R8/R9/R10 (all passed, absmax 0.0):
//   Sum(g~-t)^2 = Sum_rc n*g~^2 - 2*Sum_rc g~*S1 + Sum t^2
// R10 (strip-LDS rotate) got fused_main to ~44us but it is LATENCY-bound:
// 768 blocks = 3/CU (grid-limited), ~2 S1 waves/SIMD to hide the per-segment
// ds_read(~120cy)->acc chain. R11: split each S1 row into two half-rows
// (a in [0,128) / [128,256)) -> 1024 S1 blocks + 256 gemm = 1280 blocks =
// 5/CU co-resident (27KB LDS x 5 = 135KB < 160KB). S1 waves/SIMD 2 -> 4.
// S1 stored as 2 half-sums; final_partial adds them; t2part[1024].
//
// ws: [0,4MB) fp32 g_part[4][512*512]; [4,6MB) fp32 S1h[2][512*512];
//     fp32 t2part[1024]; fp32 partial2[256].

typedef __attribute__((ext_vector_type(8))) short bf16x8;   // 8 bf16 in 4 VGPRs
typedef __attribute__((ext_vector_type(4))) float f32x4;

#define CH 512
#define KDIM 4096
#define SPLITK 4

#define BM 64
#define BK 64
#define LDT 72   // padded LDS stride in bf16: 144 B (b128-aligned, 2-way alias = free)

static __device__ inline uint4 cvt8_bf16(float4 a, float4 b) {
    float f[8] = {a.x, a.y, a.z, a.w, b.x, b.y, b.z, b.w};
    union { ushort u[8]; uint4 v; } o;
#pragma unroll
    for (int i = 0; i < 8; ++i) {
        __hip_bfloat16 h = __float2bfloat16(f[i]);
        o.u[i] = *reinterpret_cast<ushort*>(&h);
    }
    return o.v;
}

// ---------------------------------------------------------------- fused ------
// blocks [0,1024):  S1 half-rows: r = bid>>1, half = bid&1, 128 segments/block
// blocks [1024,1280): gemm C=F*F^T (R8/R10 verbatim, proven)
__global__ __launch_bounds__(256) void fused_main_kernel(const float* __restrict__ x,
                                                         const float* __restrict__ target,
                                                         float* __restrict__ g_part,
                                                         float* __restrict__ S1g,
                                                         float* __restrict__ t2part) {
    __shared__ __hip_bfloat16 a_tile[BM * LDT];
    __shared__ __hip_bfloat16 b_tile[BM * LDT];
    __shared__ float wavebuf[4][2][256];   // per-wave double-buffered strip store
    __shared__ float comb[4][512];         // cross-wave S1 combine
    __shared__ float t2w[4];

    const int bid = blockIdx.x;
    const int tid = threadIdx.x;
    const int lane = tid & 63;
    const int w    = tid >> 6;

    if (bid >= 1024) {
        // ======================== GEMM role (R8/R10 verbatim) ========================
        const int gid = bid - 1024;
        const int bm = gid & 7, bn = (gid >> 3) & 7, kz = gid >> 6;
        const int m    = lane & 15;
        const int q    = lane >> 4;       // quad: k offset q*8
        const int srow = tid >> 3;        // staging row 0..31 (+32 for p=1)
        const int scol = (tid & 7) * 8;   // 0..56 step 8

        f32x4 acc[4] = {};

        const int NT = (KDIM / SPLITK) / BK;            // 16 k-tiles per block
        const int k0base = kz * (KDIM / SPLITK);        // 1024 per split

        const float* arow0 = x + (size_t)(bm * 64 + srow) * KDIM + k0base + scol;
        const float* brow0 = x + (size_t)(bn * 64 + srow) * KDIM + k0base + scol;

        float4 pa[2][2], pb[2][2];
#pragma unroll
        for (int p = 0; p < 2; ++p) {
            const float* ap = arow0 + (size_t)p * 32 * KDIM;
            const float* bp = brow0 + (size_t)p * 32 * KDIM;
            pa[p][0] = *(const float4*)(ap);  pa[p][1] = *(const float4*)(ap + 4);
            pb[p][0] = *(const float4*)(bp);  pb[p][1] = *(const float4*)(bp + 4);
        }

        for (int kt = 0; kt < NT; ++kt) {
            if (kt > 0) __syncthreads();
#pragma unroll
            for (int p = 0; p < 2; ++p) {
                uint4 av = cvt8_bf16(pa[p][0], pa[p][1]);
                uint4 bv = cvt8_bf16(pb[p][0], pb[p][1]);
                uint* ap = (uint*)(a_tile + (srow + p * 32) * LDT + scol);
                ap[0] = av.x; ap[1] = av.y; ap[2] = av.z; ap[3] = av.w;
                uint* bp = (uint*)(b_tile + (srow + p * 32) * LDT + scol);
                bp[0] = bv.x; bp[1] = bv.y; bp[2] = bv.z; bp[3] = bv.w;
            }
            __syncthreads();
            if (kt + 1 < NT) {
                const int ko = (kt + 1) * BK;
#pragma unroll
                for (int p = 0; p < 2; ++p) {
                    const float* ap = arow0 + (size_t)p * 32 * KDIM + ko;
                    const float* bp = brow0 + (size_t)p * 32 * KDIM + ko;
                    pa[p][0] = *(const float4*)(ap);  pa[p][1] = *(const float4*)(ap + 4);
                    pb[p][0] = *(const float4*)(bp);  pb[p][1] = *(const float4*)(bp + 4);
                }
            }
#pragma unroll
            for (int ks = 0; ks < 2; ++ks) {
                const int kk = ks * 32 + q * 8;
                bf16x8 afrag = *(const bf16x8*)(a_tile + (w * 16 + m) * LDT + kk);
#pragma unroll
                for (int j = 0; j < 4; ++j) {
                    bf16x8 bfrag = *(const bf16x8*)(b_tile + (j * 16 + m) * LDT + kk);
                    acc[j] = __builtin_amdgcn_mfma_f32_16x16x32_bf16(afrag, bfrag, acc[j], 0, 0, 0);
                }
            }
        }

        // C/D layout: col = lane&15, row = (lane>>4)*4 + reg (verified m89/m91)
        float* gp = g_part + ((size_t)kz << 18);
        const int col = lane & 15;
        const int rq  = (lane >> 4) * 4;
#pragma unroll
        for (int j = 0; j < 4; ++j) {
#pragma unroll
            for (int reg = 0; reg < 4; ++reg) {
                const int rg = bm * 64 + w * 16 + rq + reg;
                const int cg = bn * 64 + j * 16 + col;
                gp[rg * CH + cg] = acc[j][reg];
            }
        }
        return;
    }

    // ======================== S1 role: one half-row per block ========================
    // r = bid>>1, half = bid&1. Wave w: segments a = half*128 + 32w + s, s=0..31;
    // i = (r-a)&511; seg = t[i,a,0..255]. Lane L loads seg[4L..4L+3] (aligned
    // float4), strip-stores to LDS (elem p at buf[(p&3)*64 + (p>>2)], addrs
    // lane-constant => conflict-free), then gathers its cols' sources:
    // col 4L+e <- buf[((e-i)&3)*64 + (((4L-i+e)&255)>>2)], stride-1 across lanes.
    // Set select k0 = bit8((4L-i)&511) ^ wrap, branch-free cndmask.
    const int r    = bid >> 1;
    const int half = bid & 1;
    const int abase = half * 128 + 32 * w;
    const float4* tgt4 = (const float4*)target;

    float accA[4] = {}, accB[4] = {};
    float t2 = 0.0f;
    float* bufw = &wavebuf[w][0][0];                 // [2][256]

    float4 pre[4];
#pragma unroll
    for (int e = 0; e < 4; ++e) {
        const int a = abase + e;
        const int i = (r - a) & 511;
        pre[e] = tgt4[((size_t)i << 14) + (a << 6) + lane];
    }

    for (int s0 = 0; s0 < 32; s0 += 4) {
        float4 cur[4];
#pragma unroll
        for (int e = 0; e < 4; ++e) cur[e] = pre[e];
        if (s0 + 4 < 32) {
#pragma unroll
            for (int e = 0; e < 4; ++e) {
                const int a = abase + s0 + 4 + e;
                const int i = (r - a) & 511;
                pre[e] = tgt4[((size_t)i << 14) + (a << 6) + lane];
            }
        }
#pragma unroll
        for (int u = 0; u < 4; ++u) {
            const int s = s0 + u;
            const int a = abase + s;
            const int i = (r - a) & 511;
            const float4 v = cur[u];
            t2 += v.x * v.x + v.y * v.y + v.z * v.z + v.w * v.w;

            float* buf = bufw + ((s & 1) << 8);      // double buffer
            buf[lane]       = v.x;                   // strip e: addr e*64+L (const/lane)
            buf[64 + lane]  = v.y;
            buf[128 + lane] = v.z;
            buf[192 + lane] = v.w;

            const int b0  = (4 * lane - i) & 255;    // source pos for col 4L (mod 256)
            const int k00 = ((4 * lane - i) & 511) >> 8;
#pragma unroll
            for (int e = 0; e < 4; ++e) {
                const int pe   = b0 + e;             // <= 258
                const int pos  = pe & 255;
                const int k0   = k00 ^ (pe >> 8);    // set select, flips on wrap
                const float val = buf[(((e - i) & 3) << 6) | (pos >> 2)];
                accA[e] += k0 ? 0.0f : val;
                accB[e] += k0 ? val : 0.0f;
            }
        }
    }

    // cross-wave combine via LDS (once per block), then write S1 half-row + t2
    *(float4*)&comb[w][4 * lane]       = *(float4*)accA;
    *(float4*)&comb[w][4 * lane + 256] = *(float4*)accB;
#pragma unroll
    for (int off = 32; off > 0; off >>= 1) t2 += __shfl_xor(t2, off, 64);
    if (lane == 0) t2w[w] = t2;
    __syncthreads();
    const float s0c = comb[0][tid]       + comb[1][tid]       + comb[2][tid]       + comb[3][tid];
    const float s1c = comb[0][tid + 256] + comb[1][tid + 256] + comb[2][tid + 256] + comb[3][tid + 256];
    float* S1h = S1g + (size_t)half * (CH * CH);
    S1h[r * CH + tid]       = s0c;
    S1h[r * CH + tid + 256] = s1c;
    if (tid == 0) t2part[bid] = t2w[0] + t2w[1] + t2w[2] + t2w[3];
}

// ---------------------------------------------------------------- final ------
// 256 blocks x 256 threads, 4 cells/thread: g~ = sum_k g_part / 2^20;
// acc += n(r,c)*g~^2 - 2*g~*(S1h0+S1h1).  n = 256 - min((r-c)&511,(c-r)&511).
__global__ __launch_bounds__(256) void final_partial_kernel(const float* __restrict__ g_part,
                                                            const float* __restrict__ S1g,
                                                            float* __restrict__ partial2) {
    const float gscale = 1.0f / 1048576.0f;
    const int tid = threadIdx.x, bid = blockIdx.x;
    const int lane = tid & 63, wv = tid >> 6;
    const int cell = (bid * 256 + tid) * 4;          // linear rc, row-aligned (512%4==0)
    const int r = cell >> 9, c0 = cell & 511;

    float4 g = *(const float4*)(g_part + cell);
#pragma unroll
    for (int sl = 1; sl < SPLITK; ++sl) {
        float4 v = *(const float4*)(g_part + sl * (CH * CH) + cell);
        g.x += v.x; g.y += v.y; g.z += v.z; g.w += v.w;
    }
    float4 s1 = *(const float4*)(S1g + cell);
    {
        float4 v = *(const float4*)(S1g + (CH * CH) + cell);
        s1.x += v.x; s1.y += v.y; s1.z += v.z; s1.w += v.w;
    }

    float gg[4] = {g.x, g.y, g.z, g.w};
    float ss[4] = {s1.x, s1.y, s1.z, s1.w};
    float acc = 0.0f;
#pragma unroll
    for (int j = 0; j < 4; ++j) {
        const int c  = c0 + j;
        const int d1 = (r - c) & 511;
        const int d2 = (c - r) & 511;
        const float n = (float)(256 - (d1 < d2 ? d1 : d2));
        const float gt = gg[j] * gscale;
        acc += n * gt * gt - 2.0f * gt * ss[j];
    }

#pragma unroll
    for (int off = 32; off > 0; off >>= 1) acc += __shfl_xor(acc, off, 64);
    __shared__ float wsum[4];
    if (lane == 0) wsum[wv] = acc;
    __syncthreads();
    if (tid == 0) partial2[bid] = wsum[0] + wsum[1] + wsum[2] + wsum[3];
}

// ---------------------------------------------------------------- finish -----
// out = (sum partial2[256] + sum t2part[1024]) * WEIGHT/count
__global__ __launch_bounds__(256) void finish_kernel(const float* __restrict__ partial2,
                                                     const float* __restrict__ t2part,
                                                     float* __restrict__ out) {
    const float lscale = 1.0e6f / 33554432.0f;
    const int tid  = threadIdx.x;
    const int lane = tid & 63;
    const int wv   = tid >> 6;
    float s = partial2[tid] + t2part[tid] + t2part[tid + 256]
            + t2part[tid + 512] + t2part[tid + 768];
#pragma unroll
    for (int off = 32; off > 0; off >>= 1) s += __shfl_xor(s, off, 64);
    __shared__ float wsum[4];
    if (lane == 0) wsum[wv] = s;
    __syncthreads();
    if (tid == 0) out[0] = (wsum[0] + wsum[1] + wsum[2] + wsum[3]) * lscale;
}

// ---------------------------------------------------------------- launch -----
extern "C" void kernel_launch(void* const* d_in, const int* in_sizes, int n_in,
                              void* d_out, int out_size, void* d_ws, size_t ws_size,
                              hipStream_t stream) {
    const float* x      = (const float*)d_in[0];   // 2097152 fp32
    const float* target = (const float*)d_in[1];   // 33554432 fp32
    float* out = (float*)d_out;

    float* g_part   = (float*)d_ws;                     // 4 MB  [4][512*512]
    float* S1g      = g_part + SPLITK * CH * CH;        // 2 MB  [2][512*512]
    float* t2part   = S1g + 2 * CH * CH;                // 4 KB
    float* partial2 = t2part + 1024;                    // 1 KB

    fused_main_kernel<<<1280, 256, 0, stream>>>(x, target, g_part, S1g, t2part);
    final_partial_kernel<<<256, 256, 0, stream>>>(g_part, S1g, partial2);
    finish_kernel<<<1, 256, 0, stream>>>(partial2, t2part, out);
}

// Round 9
// 206.502 us; speedup vs baseline: 1.0290x; 1.0290x over previous
//
#include <hip/hip_runtime.h>
#include <hip/hip_bf16.h>

// StyleLoss — x (1,512,64,64) fp32, target (512,256,256) fp32 -> scalar loss.
// loss = mean_{i,a,b}( (g_full[(i+a)%512,(i+b)%512]/2^20 - target[i,a,b])^2 ) * 1e6
//
// R12: algebra unchanged (R8-R11 all passed, absmax 0.0):
//   Sum(g~-t)^2 = Sum_rc n*g~^2 - 2*Sum_rc g~*S1 + Sum t^2
// R10's strip-LDS rotate = 2 LDS round-trip waits per segment (~350cy chain);
// R11 (+TLP) proved the chain, not occupancy, is the limiter. R12 rotates IN
// REGISTER via ds_bpermute: rotation by i of the 256-vector (4 floats/lane)
// = lane-shuffle by sh=i>>2 plus component permutation by f=i&3:
//   out[e] = __shfl(v[(e-f)&3], lane - sh - (e<f))
// f is wave-uniform -> one uniform switch per 4-segment group (template<F0>,
// everything folds; no dynamic reg indexing). 4 bpermute + ~40 VALU/segment,
// zero ds_write, one wait. Set select k = bit8((4L+e-i)&511) as before.
// Grid back to R10's 768 (512 S1 rows + 256 gemm).
//
// ws: [0,4MB) fp32 g_part[4][512*512]; [4,5MB) fp32 S1[512][512];
//     fp32 t2part[512]; fp32 partial2[256].

typedef __attribute__((ext_vector_type(8))) short bf16x8;   // 8 bf16 in 4 VGPRs
typedef __attribute__((ext_vector_type(4))) float f32x4;

#define CH 512
#define KDIM 4096
#define SPLITK 4

#define BM 64
#define BK 64
#define LDT 72   // padded LDS stride in bf16: 144 B (b128-aligned, 2-way alias = free)

static __device__ inline uint4 cvt8_bf16(float4 a, float4 b) {
    float f[8] = {a.x, a.y, a.z, a.w, b.x, b.y, b.z, b.w};
    union { ushort u[8]; uint4 v; } o;
#pragma unroll
    for (int i = 0; i < 8; ++i) {
        __hip_bfloat16 h = __float2bfloat16(f[i]);
        o.u[i] = *reinterpret_cast<ushort*>(&h);
    }
    return o.v;
}

static __device__ inline float vcomp(const float4& v, int c) {
    // compile-time c only (called from fully-unrolled context)
    return c == 0 ? v.x : c == 1 ? v.y : c == 2 ? v.z : v.w;
}

// Process 4 segments (u=0..3) whose f = (F0-u)&3 is compile-time.
template<int F0>
static __device__ inline void s1_quad(const float4* cur, int r, int a0, int lane,
                                      float* accA, float* accB, float& t2) {
#pragma unroll
    for (int u = 0; u < 4; ++u) {
        const int f = (F0 - u) & 3;                  // folds per unrolled u
        const int a = a0 + u;
        const int i = (r - a) & 511;
        const int sh = i >> 2;
        const float4 v = cur[u];
        t2 += v.x * v.x + v.y * v.y + v.z * v.z + v.w * v.w;

        const int s2 = lane - sh;
        float out[4];
#pragma unroll
        for (int e = 0; e < 4; ++e) {                // e, f, c all compile-time
            const int c = (e - f) & 3;
            const int carry = (e < f) ? 1 : 0;
            out[e] = __shfl(vcomp(v, c), (s2 - carry) & 63, 64);
        }
        const int d0 = (4 * lane - i) & 511;
#pragma unroll
        for (int e = 0; e < 4; ++e) {
            const int k = ((d0 + e) & 511) >> 8;     // set select (bit8)
            accA[e] += k ? 0.0f : out[e];
            accB[e] += k ? out[e] : 0.0f;
        }
    }
}

// ---------------------------------------------------------------- fused ------
// blocks [0,512): S1 rows; blocks [512,768): gemm C=F*F^T (R8/R10 verbatim).
__global__ __launch_bounds__(256) void fused_main_kernel(const float* __restrict__ x,
                                                         const float* __restrict__ target,
                                                         float* __restrict__ g_part,
                                                         float* __restrict__ S1g,
                                                         float* __restrict__ t2part) {
    __shared__ __hip_bfloat16 a_tile[BM * LDT];
    __shared__ __hip_bfloat16 b_tile[BM * LDT];
    __shared__ float comb[4][512];         // cross-wave S1 combine
    __shared__ float t2w[4];

    const int bid = blockIdx.x;
    const int tid = threadIdx.x;
    const int lane = tid & 63;
    const int w    = tid >> 6;

    if (bid >= 512) {
        // ======================== GEMM role (R8/R10 verbatim, proven) ========================
        const int gid = bid - 512;
        const int bm = gid & 7, bn = (gid >> 3) & 7, kz = gid >> 6;
        const int m    = lane & 15;
        const int q    = lane >> 4;       // quad: k offset q*8
        const int srow = tid >> 3;        // staging row 0..31 (+32 for p=1)
        const int scol = (tid & 7) * 8;   // 0..56 step 8

        f32x4 acc[4] = {};

        const int NT = (KDIM / SPLITK) / BK;            // 16 k-tiles per block
        const int k0base = kz * (KDIM / SPLITK);        // 1024 per split

        const float* arow0 = x + (size_t)(bm * 64 + srow) * KDIM + k0base + scol;
        const float* brow0 = x + (size_t)(bn * 64 + srow) * KDIM + k0base + scol;

        float4 pa[2][2], pb[2][2];
#pragma unroll
        for (int p = 0; p < 2; ++p) {
            const float* ap = arow0 + (size_t)p * 32 * KDIM;
            const float* bp = brow0 + (size_t)p * 32 * KDIM;
            pa[p][0] = *(const float4*)(ap);  pa[p][1] = *(const float4*)(ap + 4);
            pb[p][0] = *(const float4*)(bp);  pb[p][1] = *(const float4*)(bp + 4);
        }

        for (int kt = 0; kt < NT; ++kt) {
            if (kt > 0) __syncthreads();
#pragma unroll
            for (int p = 0; p < 2; ++p) {
                uint4 av = cvt8_bf16(pa[p][0], pa[p][1]);
                uint4 bv = cvt8_bf16(pb[p][0], pb[p][1]);
                uint* ap = (uint*)(a_tile + (srow + p * 32) * LDT + scol);
                ap[0] = av.x; ap[1] = av.y; ap[2] = av.z; ap[3] = av.w;
                uint* bp = (uint*)(b_tile + (srow + p * 32) * LDT + scol);
                bp[0] = bv.x; bp[1] = bv.y; bp[2] = bv.z; bp[3] = bv.w;
            }
            __syncthreads();
            if (kt + 1 < NT) {
                const int ko = (kt + 1) * BK;
#pragma unroll
                for (int p = 0; p < 2; ++p) {
                    const float* ap = arow0 + (size_t)p * 32 * KDIM + ko;
                    const float* bp = brow0 + (size_t)p * 32 * KDIM + ko;
                    pa[p][0] = *(const float4*)(ap);  pa[p][1] = *(const float4*)(ap + 4);
                    pb[p][0] = *(const float4*)(bp);  pb[p][1] = *(const float4*)(bp + 4);
                }
            }
#pragma unroll
            for (int ks = 0; ks < 2; ++ks) {
                const int kk = ks * 32 + q * 8;
                bf16x8 afrag = *(const bf16x8*)(a_tile + (w * 16 + m) * LDT + kk);
#pragma unroll
                for (int j = 0; j < 4; ++j) {
                    bf16x8 bfrag = *(const bf16x8*)(b_tile + (j * 16 + m) * LDT + kk);
                    acc[j] = __builtin_amdgcn_mfma_f32_16x16x32_bf16(afrag, bfrag, acc[j], 0, 0, 0);
                }
            }
        }

        // C/D layout: col = lane&15, row = (lane>>4)*4 + reg (verified m89/m91)
        float* gp = g_part + ((size_t)kz << 18);
        const int col = lane & 15;
        const int rq  = (lane >> 4) * 4;
#pragma unroll
        for (int j = 0; j < 4; ++j) {
#pragma unroll
            for (int reg = 0; reg < 4; ++reg) {
                const int rg = bm * 64 + w * 16 + rq + reg;
                const int cg = bn * 64 + j * 16 + col;
                gp[rg * CH + cg] = acc[j][reg];
            }
        }
        return;
    }

    // ======================== S1 role: one output row r per block ========================
    // Wave w: segments a = 64w+s, s=0..63; i=(r-a)&511; seg = t[i,a,0..255].
    // Lane L loads seg[4L..4L+3]; rotation by i done IN REGISTER via shuffle
    // (see s1_quad). accA[e] = col 4L+e, accB[e] = col 256+4L+e.
    const int r = bid;
    const int abase = 64 * w;
    const float4* tgt4 = (const float4*)target;

    float accA[4] = {}, accB[4] = {};
    float t2 = 0.0f;

    float4 pre[4];
#pragma unroll
    for (int e = 0; e < 4; ++e) {
        const int a = abase + e;
        const int i = (r - a) & 511;
        pre[e] = tgt4[((size_t)i << 14) + (a << 6) + lane];
    }

    for (int s0 = 0; s0 < 64; s0 += 4) {
        float4 cur[4];
#pragma unroll
        for (int e = 0; e < 4; ++e) cur[e] = pre[e];
        if (s0 + 4 < 64) {
#pragma unroll
            for (int e = 0; e < 4; ++e) {
                const int a = abase + s0 + 4 + e;
                const int i = (r - a) & 511;
                pre[e] = tgt4[((size_t)i << 14) + (a << 6) + lane];
            }
        }
        const int a0 = abase + s0;
        const int f0 = (r - a0) & 3;                 // wave-uniform branch
        switch (f0) {
            case 0: s1_quad<0>(cur, r, a0, lane, accA, accB, t2); break;
            case 1: s1_quad<1>(cur, r, a0, lane, accA, accB, t2); break;
            case 2: s1_quad<2>(cur, r, a0, lane, accA, accB, t2); break;
            default: s1_quad<3>(cur, r, a0, lane, accA, accB, t2); break;
        }
    }

    // cross-wave combine via LDS (once per block), then write S1 row + t2
    *(float4*)&comb[w][4 * lane]       = *(float4*)accA;
    *(float4*)&comb[w][4 * lane + 256] = *(float4*)accB;
#pragma unroll
    for (int off = 32; off > 0; off >>= 1) t2 += __shfl_xor(t2, off, 64);
    if (lane == 0) t2w[w] = t2;
    __syncthreads();
    const float s0c = comb[0][tid]       + comb[1][tid]       + comb[2][tid]       + comb[3][tid];
    const float s1c = comb[0][tid + 256] + comb[1][tid + 256] + comb[2][tid + 256] + comb[3][tid + 256];
    S1g[r * CH + tid]       = s0c;
    S1g[r * CH + tid + 256] = s1c;
    if (tid == 0) t2part[r] = t2w[0] + t2w[1] + t2w[2] + t2w[3];
}

// ---------------------------------------------------------------- final ------
// 256 blocks x 256 threads, 4 cells/thread: g~ = sum_k g_part / 2^20;
// acc += n(r,c)*g~^2 - 2*g~*S1.   n = 256 - min((r-c)&511,(c-r)&511).
__global__ __launch_bounds__(256) void final_partial_kernel(const float* __restrict__ g_part,
                                                            const float* __restrict__ S1g,
                                                            float* __restrict__ partial2) {
    const float gscale = 1.0f / 1048576.0f;
    const int tid = threadIdx.x, bid = blockIdx.x;
    const int lane = tid & 63, wv = tid >> 6;
    const int cell = (bid * 256 + tid) * 4;          // linear rc, row-aligned (512%4==0)
    const int r = cell >> 9, c0 = cell & 511;

    float4 g = *(const float4*)(g_part + cell);
#pragma unroll
    for (int sl = 1; sl < SPLITK; ++sl) {
        float4 v = *(const float4*)(g_part + sl * (CH * CH) + cell);
        g.x += v.x; g.y += v.y; g.z += v.z; g.w += v.w;
    }
    float4 s1 = *(const float4*)(S1g + cell);

    float gg[4] = {g.x, g.y, g.z, g.w};
    float ss[4] = {s1.x, s1.y, s1.z, s1.w};
    float acc = 0.0f;
#pragma unroll
    for (int j = 0; j < 4; ++j) {
        const int c  = c0 + j;
        const int d1 = (r - c) & 511;
        const int d2 = (c - r) & 511;
        const float n = (float)(256 - (d1 < d2 ? d1 : d2));
        const float gt = gg[j] * gscale;
        acc += n * gt * gt - 2.0f * gt * ss[j];
    }

#pragma unroll
    for (int off = 32; off > 0; off >>= 1) acc += __shfl_xor(acc, off, 64);
    __shared__ float wsum[4];
    if (lane == 0) wsum[wv] = acc;
    __syncthreads();
    if (tid == 0) partial2[bid] = wsum[0] + wsum[1] + wsum[2] + wsum[3];
}

// ---------------------------------------------------------------- finish -----
// out = (sum partial2[256] + sum t2part[512]) * WEIGHT/count
__global__ __launch_bounds__(256) void finish_kernel(const float* __restrict__ partial2,
                                                     const float* __restrict__ t2part,
                                                     float* __restrict__ out) {
    const float lscale = 1.0e6f / 33554432.0f;
    const int tid  = threadIdx.x;
    const int lane = tid & 63;
    const int wv   = tid >> 6;
    float s = partial2[tid] + t2part[tid] + t2part[tid + 256];
#pragma unroll
    for (int off = 32; off > 0; off >>= 1) s += __shfl_xor(s, off, 64);
    __shared__ float wsum[4];
    if (lane == 0) wsum[wv] = s;
    __syncthreads();
    if (tid == 0) out[0] = (wsum[0] + wsum[1] + wsum[2] + wsum[3]) * lscale;
}

// ---------------------------------------------------------------- launch -----
extern "C" void kernel_launch(void* const* d_in, const int* in_sizes, int n_in,
                              void* d_out, int out_size, void* d_ws, size_t ws_size,
                              hipStream_t stream) {
    const float* x      = (const float*)d_in[0];   // 2097152 fp32
    const float* target = (const float*)d_in[1];   // 33554432 fp32
    float* out = (float*)d_out;

    float* g_part   = (float*)d_ws;                     // 4 MB  [4][512*512]
    float* S1g      = g_part + SPLITK * CH * CH;        // 1 MB  [512][512]
    float* t2part   = S1g + CH * CH;                    // 2 KB
    float* partial2 = t2part + CH;                      // 1 KB

    fused_main_kernel<<<768, 256, 0, stream>>>(x, target, g_part, S1g, t2part);
    final_partial_kernel<<<256, 256, 0, stream>>>(g_part, S1g, partial2);
    finish_kernel<<<1, 256, 0, stream>>>(partial2, t2part, out);
}